// Round 10
// baseline (124.371 us; speedup 1.0000x reference)
//
#include <hip/hip_runtime.h>
#include <hip/hip_bf16.h>
#include <math.h>

#define D_   64
#define HW_  4096
#define N_   16384
#define M_   4096

#define NSPLIT  16             // n-splits
#define NCHUNK  1024           // rows per block
#define NTILES  8              // 8 tiles of 128 rows (4 waves x 32)
#define NBLOCKS 512            // 32 mblk x 16 ns

// ws layout (floats)
#define AEN_OFF 0              // aen'[4096] (log2 domain)
#define SUM_OFF 4096           // sums[4096] (memset to 0 each launch)
#define CNT_OFF 8192           // completion counter (memset to 0)

#define L2E 1.4426950408889634f
#define LN2 0.6931471805599453

typedef __attribute__((ext_vector_type(8))) short short8;
typedef __attribute__((ext_vector_type(16))) float floatx16;

#if __has_builtin(__builtin_amdgcn_exp2f)
#define EXP2F(x) __builtin_amdgcn_exp2f(x)
#else
#define EXP2F(x) exp2f(x)
#endif

__device__ __forceinline__ unsigned pk2(float lo, float hi) {
    union { __hip_bfloat162 h; unsigned u; } c;
    c.h = __float22bfloat162_rn(make_float2(lo, hi));
    return c.u;
}

__device__ __forceinline__ short8 pack8(const float* v, float s) {
    union { unsigned u[4]; short8 o; } r;
    r.u[0] = pk2(v[0] * s, v[1] * s);
    r.u[1] = pk2(v[2] * s, v[3] * s);
    r.u[2] = pk2(v[4] * s, v[5] * s);
    r.u[3] = pk2(v[6] * s, v[7] * s);
    return r.o;
}

// Single fused kernel: B(e) conversion + aen in registers, A(z) fragments loaded
// directly from native [b][d][hw] layout (coalesced across lanes), fused exp2
// epilogue, global atomic column sums, last-arriving block finalizes.
__global__ __launch_bounds__(256, 2) void fused_main(
        const float* __restrict__ z, const float* __restrict__ e,
        const float* __restrict__ lsp, float* __restrict__ ws,
        float* __restrict__ out) {
    __shared__ float red[128];
    __shared__ double dred[256];
    __shared__ int is_last;

    const int t = threadIdx.x;
    const int lane = t & 63;
    const int w = t >> 6;
    const int rlo = lane & 31;
    const int kh = lane >> 5;
    const int mblk = blockIdx.x;   // 0..31
    const int ns = blockIdx.y;     // 0..15
    const int m0 = mblk * 128;

    const float ls = lsp[0];
    const float alpha = -0.5f * __expf(-2.f * ls);   // -1/(2 e^{2ls})
    const float anl = alpha * L2E;                   // norm scale (log2 domain)
    const float c2p = -2.f * alpha * L2E;            // z pre-scale (log2 domain)

    float* aenp = ws + AEN_OFF;
    float* sums = ws + SUM_OFF;
    unsigned* cnt = (unsigned*)(ws + CNT_OFF);

    // ---- B: convert own 128 e-rows to bf16 frags in registers + aen ----
    short8 bf[4][4];
#pragma unroll
    for (int mt = 0; mt < 4; ++mt) {
        const float* ep = e + (size_t)(m0 + mt * 32 + rlo) * 64 + kh * 8;
        float es = 0.f;
#pragma unroll
        for (int ks = 0; ks < 4; ++ks) {
            float v[8];
            *(float4*)&v[0] = *(const float4*)(ep + ks * 16);
            *(float4*)&v[4] = *(const float4*)(ep + ks * 16 + 4);
#pragma unroll
            for (int j = 0; j < 8; ++j) es = fmaf(v[j], v[j], es);
            bf[mt][ks] = pack8(v, 1.0f);
        }
        es += __shfl_xor(es, 32);
        if (ns == 0 && lane < 32) aenp[m0 + mt * 32 + rlo] = anl * es;
    }

    // ---- main loop over 8 z-tiles (direct loads from native z layout) ----
    const int b = ns >> 2;
    const float* zp = z + ((size_t)(b * 64 + kh * 8)) * HW_
                      + (ns & 3) * 1024 + w * 32 + rlo;
    float sum[4] = {0.f, 0.f, 0.f, 0.f};

#pragma unroll
    for (int tile = 0; tile < NTILES; ++tile) {
        const int hwoff = tile * 128;
        float av[4][8];
#pragma unroll
        for (int ks = 0; ks < 4; ++ks)
#pragma unroll
            for (int j = 0; j < 8; ++j)
                av[ks][j] = zp[(size_t)(ks * 16 + j) * HW_ + hwoff];

        // row norm (this lane's kh-half, folded with the other half)
        float zs = 0.f;
#pragma unroll
        for (int ks = 0; ks < 4; ++ks)
#pragma unroll
            for (int j = 0; j < 8; ++j) zs = fmaf(av[ks][j], av[ks][j], zs);
        zs += __shfl_xor(zs, 32);
        const float myazn = anl * zs;   // azn' of row rlo (tile-local)

        // bf16 fragments (pre-scaled into log2 domain)
        short8 af[4];
#pragma unroll
        for (int ks = 0; ks < 4; ++ks) af[ks] = pack8(av[ks], c2p);

        // azn for this lane's 16 C-rows via cross-lane broadcast
        float azn_r[16];
#pragma unroll
        for (int r = 0; r < 16; ++r)
            azn_r[r] = __shfl(myazn, 4 * kh + (r & 3) + 8 * (r >> 2));

        floatx16 acc[4];
#pragma unroll
        for (int mt = 0; mt < 4; ++mt)
#pragma unroll
            for (int r = 0; r < 16; ++r)
                acc[mt][r] = azn_r[r];            // aen factored out

#pragma unroll
        for (int ks = 0; ks < 4; ++ks)
#pragma unroll
            for (int mt = 0; mt < 4; ++mt)
                acc[mt] = __builtin_amdgcn_mfma_f32_32x32x16_bf16(
                    af[ks], bf[mt][ks], acc[mt], 0, 0, 0);

#pragma unroll
        for (int mt = 0; mt < 4; ++mt) {
            float s = 0.f;
#pragma unroll
            for (int r = 0; r < 16; ++r) s += EXP2F(acc[mt][r]);
            sum[mt] += s;
        }
    }

    // ---- column-sum reduction: fold halves, LDS, one global atomic per m ----
#pragma unroll
    for (int mt = 0; mt < 4; ++mt) sum[mt] += __shfl_down(sum[mt], 32);

    if (t < 128) red[t] = 0.f;
    __syncthreads();
    if (lane < 32) {
#pragma unroll
        for (int mt = 0; mt < 4; ++mt) atomicAdd(&red[mt * 32 + rlo], sum[mt]);
    }
    __syncthreads();
    if (t < 128) atomicAdd(&sums[m0 + t], red[t]);

    // ---- last-arriving block finalizes ----
    __threadfence();
    __syncthreads();
    if (t == 0) {
        unsigned old = __hip_atomic_fetch_add(cnt, 1u, __ATOMIC_ACQ_REL,
                                              __HIP_MEMORY_SCOPE_AGENT);
        is_last = (old == NBLOCKS - 1);
    }
    __syncthreads();
    if (is_last) {
        __threadfence();
        double local = 0.0;
#pragma unroll
        for (int j = 0; j < 16; ++j) {
            int m = t + 256 * j;
            float s = __hip_atomic_load(&sums[m], __ATOMIC_RELAXED,
                                        __HIP_MEMORY_SCOPE_AGENT);
            float a = __hip_atomic_load(&aenp[m], __ATOMIC_RELAXED,
                                        __HIP_MEMORY_SCOPE_AGENT);
            local += (double)(a + log2f(s));      // lse_m / ln2
        }
        dred[t] = local;
        __syncthreads();
        for (int off = 128; off > 0; off >>= 1) {
            if (t < off) dred[t] += dred[t + off];
            __syncthreads();
        }
        if (t == 0) {
            double lsd = (double)ls;
            double loss = -(LN2 * dred[0] / (double)M_)
                          + 0.5 * (double)D_ * (2.0 * lsd - 1.0)
                          + log((double)N_);
            out[0] = (float)loss;
        }
    }
}

extern "C" void kernel_launch(void* const* d_in, const int* in_sizes, int n_in,
                              void* d_out, int out_size, void* d_ws, size_t ws_size,
                              hipStream_t stream) {
    const float* z   = (const float*)d_in[0];
    const float* e   = (const float*)d_in[1];
    const float* lsp = (const float*)d_in[2];
    float* ws  = (float*)d_ws;
    float* out = (float*)d_out;

    // zero sums[4096] + counter (graph-capturable memset node)
    hipMemsetAsync((char*)d_ws + SUM_OFF * sizeof(float), 0,
                   4096 * sizeof(float) + 16, stream);
    hipLaunchKernelGGL(fused_main, dim3(32, NSPLIT), dim3(256), 0, stream,
                       z, e, lsp, ws, out);
}

// Round 11
// 122.253 us; speedup vs baseline: 1.0173x; 1.0173x over previous
//
#include <hip/hip_runtime.h>
#include <hip/hip_bf16.h>
#include <math.h>

#define D_   64
#define HW_  4096
#define N_   16384
#define M_   4096

#define NSPLIT  16             // n-splits
#define NCHUNK  1024           // rows per block
#define NSTEPS  16             // 16 steps of 64 rows (4 waves x 16)
#define NBLOCKS 512            // 32 mblk x 16 ns

// ---- ws layout (floats) ----
#define AZN_OFF 0                      // azn'[16384] (log2-domain row norms)
#define AEN_OFF 16384                  // aen'[4096]  (log2-domain col norms)
#define SUM_OFF 20480                  // sums[4096]  (memset-zeroed)
#define CNT_OFF 24576                  // counter (memset-zeroed) + pad
#define ZTB_OFF 24584                  // zT bf16 [16384][64] = 524288 floats
#define EBF_OFF (24584 + 524288)       // e  bf16 [4096][64]

#define L2E 1.4426950408889634f
#define LN2 0.6931471805599453

typedef __attribute__((ext_vector_type(8))) short short8;
typedef __attribute__((ext_vector_type(4))) float floatx4;

#if __has_builtin(__builtin_amdgcn_exp2f)
#define EXP2F(x) __builtin_amdgcn_exp2f(x)
#else
#define EXP2F(x) exp2f(x)
#endif

__device__ __forceinline__ unsigned int bf16_rne(float x) {
    unsigned int u = __float_as_uint(x);
    u += 0x7fffu + ((u >> 16) & 1u);
    return u >> 16;
}

// blocks 0..255: z transpose+scale+norm ; blocks 256..271: e convert+norm
__global__ void prep_kernel(const float* __restrict__ z,
                            const float* __restrict__ e,
                            const float* __restrict__ lsp,
                            float* __restrict__ ws) {
    const float ls = lsp[0];
    const float alpha = -0.5f * __expf(-2.f * ls);   // -1/(2 e^{2ls})
    const float anl = alpha * L2E;                   // norm scale (log2 domain)
    const float c2p = -2.f * alpha * L2E;            // z pre-scale (log2 domain)
    unsigned short* zTb = (unsigned short*)(ws + ZTB_OFF);
    unsigned short* ebf = (unsigned short*)(ws + EBF_OFF);
    const int blk = blockIdx.x, t = threadIdx.x;

    if (blk < 256) {
        __shared__ float lt[64 * 65];
        const int b = blk >> 6, hw0 = (blk & 63) * 64;
        const int n0 = b * HW_ + hw0;
        const float* zb = z + ((size_t)b * D_) * HW_ + hw0;
#pragma unroll
        for (int i = 0; i < 4; ++i) {
            int idx = t + 256 * i;
            int d = idx >> 4, c = (idx & 15) * 4;
            float4 v = *(const float4*)(zb + (size_t)d * HW_ + c);
            float* p = &lt[d * 65 + c];
            p[0] = v.x; p[1] = v.y; p[2] = v.z; p[3] = v.w;
        }
        __syncthreads();
#pragma unroll
        for (int j = 0; j < 2; ++j) {
            int idx = t + 256 * j;
            int nl = idx >> 3, g = idx & 7;
            float v[8]; float s = 0.f;
#pragma unroll
            for (int jj = 0; jj < 8; ++jj) {
                v[jj] = lt[(8 * g + jj) * 65 + nl];
                s = fmaf(v[jj], v[jj], s);
            }
            s += __shfl_xor(s, 1);
            s += __shfl_xor(s, 2);
            s += __shfl_xor(s, 4);
            uint4 pk;
            pk.x = bf16_rne(v[0] * c2p) | (bf16_rne(v[1] * c2p) << 16);
            pk.y = bf16_rne(v[2] * c2p) | (bf16_rne(v[3] * c2p) << 16);
            pk.z = bf16_rne(v[4] * c2p) | (bf16_rne(v[5] * c2p) << 16);
            pk.w = bf16_rne(v[6] * c2p) | (bf16_rne(v[7] * c2p) << 16);
            *(uint4*)(zTb + (size_t)(n0 + nl) * 64 + 8 * g) = pk;
            if (g == 0) ws[AZN_OFF + n0 + nl] = anl * s;
        }
    } else {
        int m = (blk - 256) * 256 + t;
        const float4* ep = (const float4*)(e + (size_t)m * D_);
        float s = 0.f;
        unsigned int pk[32];
#pragma unroll
        for (int k = 0; k < 16; ++k) {
            float4 v = ep[k];
            s += v.x * v.x + v.y * v.y + v.z * v.z + v.w * v.w;
            pk[2 * k]     = bf16_rne(v.x) | (bf16_rne(v.y) << 16);
            pk[2 * k + 1] = bf16_rne(v.z) | (bf16_rne(v.w) << 16);
        }
        uint4* op = (uint4*)(ebf + (size_t)m * 64);
#pragma unroll
        for (int k = 0; k < 8; ++k)
            op[k] = make_uint4(pk[4 * k], pk[4 * k + 1], pk[4 * k + 2], pk[4 * k + 3]);
        ws[AEN_OFF + m] = anl * s;
    }
}

// grid (32,16): 16x16x32 MFMA; B (128 e-rows) register-resident; 16 steps of
// 64 rows with register double-buffer prefetch; last-arriving block finalizes.
__global__ __launch_bounds__(256, 3) void main_fast(
        const float* __restrict__ lsp, float* __restrict__ ws,
        float* __restrict__ out) {
    __shared__ float red[128];
    __shared__ double dred[256];
    __shared__ int is_last;

    const int t = threadIdx.x;
    const int lane = t & 63;
    const int w = t >> 6;
    const int li = lane & 15;      // m-col / n-row local index
    const int q  = lane >> 4;      // quad: k-chunk select, C-row group
    const int mblk = blockIdx.x;   // 0..31
    const int ns = blockIdx.y;     // 0..15
    const int m0 = mblk * 128;

    const unsigned short* zTb = (const unsigned short*)(ws + ZTB_OFF);
    const unsigned short* ebf = (const unsigned short*)(ws + EBF_OFF);
    const float* azn = ws + AZN_OFF;
    float* sums = ws + SUM_OFF;
    unsigned* cnt = (unsigned*)(ws + CNT_OFF);

    // B fragments: 8 m-tiles x 2 k-steps, b128 loads (64 VGPR)
    short8 bf[8][2];
#pragma unroll
    for (int mt = 0; mt < 8; ++mt) {
        const size_t rb = (size_t)(m0 + mt * 16 + li) * 64 + q * 8;
#pragma unroll
        for (int s = 0; s < 2; ++s)
            bf[mt][s] = *(const short8*)(ebf + rb + s * 32);
    }

    float sum[8] = {0.f, 0.f, 0.f, 0.f, 0.f, 0.f, 0.f, 0.f};
    const int nwbase = ns * NCHUNK + w * 16;

    // prefetch step 0
    short8 afc[2];
    floatx4 aznc;
    {
        const size_t rb = (size_t)(nwbase + li) * 64 + q * 8;
        afc[0] = *(const short8*)(zTb + rb);
        afc[1] = *(const short8*)(zTb + rb + 32);
        aznc = *(const floatx4*)(azn + nwbase + q * 4);
    }

#pragma unroll
    for (int step = 0; step < NSTEPS; ++step) {
        short8 afn[2];
        floatx4 aznn;
        if (step + 1 < NSTEPS) {
            const int nr = nwbase + (step + 1) * 64;
            const size_t rb = (size_t)(nr + li) * 64 + q * 8;
            afn[0] = *(const short8*)(zTb + rb);
            afn[1] = *(const short8*)(zTb + rb + 32);
            aznn = *(const floatx4*)(azn + nr + q * 4);
        }

        floatx4 acc[8];
#pragma unroll
        for (int mt = 0; mt < 8; ++mt) acc[mt] = aznc;   // aen factored out

#pragma unroll
        for (int s = 0; s < 2; ++s)
#pragma unroll
            for (int mt = 0; mt < 8; ++mt)
                acc[mt] = __builtin_amdgcn_mfma_f32_16x16x32_bf16(
                    afc[s], bf[mt][s], acc[mt], 0, 0, 0);

#pragma unroll
        for (int mt = 0; mt < 8; ++mt) {
            float s0 = EXP2F(acc[mt][0]) + EXP2F(acc[mt][1]);
            float s1 = EXP2F(acc[mt][2]) + EXP2F(acc[mt][3]);
            sum[mt] += s0 + s1;
        }

        afc[0] = afn[0]; afc[1] = afn[1]; aznc = aznn;
    }

    // reduce across quads (rows): all lanes end with the column total
#pragma unroll
    for (int mt = 0; mt < 8; ++mt) {
        sum[mt] += __shfl_xor(sum[mt], 16);
        sum[mt] += __shfl_xor(sum[mt], 32);
    }

    if (t < 128) red[t] = 0.f;
    __syncthreads();
    if (lane < 16) {
#pragma unroll
        for (int mt = 0; mt < 8; ++mt) atomicAdd(&red[mt * 16 + li], sum[mt]);
    }
    __syncthreads();
    if (t < 128) atomicAdd(&sums[m0 + t], red[t]);

    // ---- last-arriving block finalizes (R10-proven pattern) ----
    __threadfence();
    __syncthreads();
    if (t == 0) {
        unsigned old = __hip_atomic_fetch_add(cnt, 1u, __ATOMIC_ACQ_REL,
                                              __HIP_MEMORY_SCOPE_AGENT);
        is_last = (old == NBLOCKS - 1);
    }
    __syncthreads();
    if (is_last) {
        __threadfence();
        const float* aenp = ws + AEN_OFF;
        double local = 0.0;
#pragma unroll
        for (int j = 0; j < 16; ++j) {
            int m = t + 256 * j;
            float s = __hip_atomic_load(&sums[m], __ATOMIC_RELAXED,
                                        __HIP_MEMORY_SCOPE_AGENT);
            local += (double)(aenp[m] + log2f(s));   // lse_m / ln2
        }
        dred[t] = local;
        __syncthreads();
        for (int off = 128; off > 0; off >>= 1) {
            if (t < off) dred[t] += dred[t + off];
            __syncthreads();
        }
        if (t == 0) {
            double lsd = (double)lsp[0];
            double loss = -(LN2 * dred[0] / (double)M_)
                          + 0.5 * (double)D_ * (2.0 * lsd - 1.0)
                          + log((double)N_);
            out[0] = (float)loss;
        }
    }
}

extern "C" void kernel_launch(void* const* d_in, const int* in_sizes, int n_in,
                              void* d_out, int out_size, void* d_ws, size_t ws_size,
                              hipStream_t stream) {
    const float* z   = (const float*)d_in[0];
    const float* e   = (const float*)d_in[1];
    const float* lsp = (const float*)d_in[2];
    float* ws  = (float*)d_ws;
    float* out = (float*)d_out;

    // zero sums[4096] + counter (graph-capturable memset node)
    hipMemsetAsync((char*)d_ws + SUM_OFF * sizeof(float), 0,
                   4096 * sizeof(float) + 32, stream);
    hipLaunchKernelGGL(prep_kernel, dim3(272), dim3(256), 0, stream, z, e, lsp, ws);
    hipLaunchKernelGGL(main_fast, dim3(32, NSPLIT), dim3(256), 0, stream,
                       lsp, ws, out);
}

// Round 12
// 93.213 us; speedup vs baseline: 1.3343x; 1.3115x over previous
//
#include <hip/hip_runtime.h>
#include <hip/hip_bf16.h>
#include <math.h>

#define D_   64
#define HW_  4096
#define N_   16384
#define M_   4096

// ---- geometry ----
#define BM 128                 // codes per block (e-rows register-resident)
#define NSPLIT 64              // n-splits across grid
#define NCHUNK (N_ / NSPLIT)   // 256 rows per block
#define NTILES 2               // 2 tiles of 128 rows (4 waves x 32), fully preloaded

// ---- ws layout (floats) ----
#define AZN_OFF 0                      // azn'[16384]  (log2-domain row norms)
#define AEN_OFF 16384                  // aen'[4096]   (log2-domain col norms)
#define SUM_OFF 20480                  // sums[4096]
#define ZTB_OFF 24576                  // zT bf16 [16384][64] = 524288 floats
#define EBF_OFF (24576 + 524288)       // e  bf16 [4096][64]  = 131072 floats

#define L2E 1.4426950408889634f
#define LN2 0.6931471805599453

typedef __attribute__((ext_vector_type(8))) short short8;
typedef __attribute__((ext_vector_type(16))) float floatx16;

#if __has_builtin(__builtin_amdgcn_exp2f)
#define EXP2F(x) __builtin_amdgcn_exp2f(x)
#else
#define EXP2F(x) exp2f(x)
#endif

__device__ __forceinline__ unsigned int bf16_rne(float x) {
    unsigned int u = __float_as_uint(x);
    u += 0x7fffu + ((u >> 16) & 1u);
    return u >> 16;
}

// blocks 0..255: z transpose+scale+norm ; blocks 256..271: e convert+norm+zero sums
__global__ void prep_kernel(const float* __restrict__ z,
                            const float* __restrict__ e,
                            const float* __restrict__ lsp,
                            float* __restrict__ ws) {
    const float ls = lsp[0];
    const float alpha = -0.5f * __expf(-2.f * ls);   // -1/(2 e^{2ls})
    const float anl = alpha * L2E;                   // norm scale (log2 domain)
    const float c2p = -2.f * alpha * L2E;            // z pre-scale (log2 domain)
    unsigned short* zTb = (unsigned short*)(ws + ZTB_OFF);
    unsigned short* ebf = (unsigned short*)(ws + EBF_OFF);
    const int blk = blockIdx.x, t = threadIdx.x;

    if (blk < 256) {
        __shared__ float lt[64 * 65];
        const int b = blk >> 6, hw0 = (blk & 63) * 64;
        const int n0 = b * HW_ + hw0;
        const float* zb = z + ((size_t)b * D_) * HW_ + hw0;
#pragma unroll
        for (int i = 0; i < 4; ++i) {
            int idx = t + 256 * i;
            int d = idx >> 4, c = (idx & 15) * 4;
            float4 v = *(const float4*)(zb + (size_t)d * HW_ + c);
            float* p = &lt[d * 65 + c];
            p[0] = v.x; p[1] = v.y; p[2] = v.z; p[3] = v.w;
        }
        __syncthreads();
#pragma unroll
        for (int j = 0; j < 2; ++j) {
            int idx = t + 256 * j;
            int nl = idx >> 3, g = idx & 7;
            float v[8]; float s = 0.f;
#pragma unroll
            for (int jj = 0; jj < 8; ++jj) {
                v[jj] = lt[(8 * g + jj) * 65 + nl];
                s = fmaf(v[jj], v[jj], s);
            }
            s += __shfl_xor(s, 1);
            s += __shfl_xor(s, 2);
            s += __shfl_xor(s, 4);
            uint4 pk;
            pk.x = bf16_rne(v[0] * c2p) | (bf16_rne(v[1] * c2p) << 16);
            pk.y = bf16_rne(v[2] * c2p) | (bf16_rne(v[3] * c2p) << 16);
            pk.z = bf16_rne(v[4] * c2p) | (bf16_rne(v[5] * c2p) << 16);
            pk.w = bf16_rne(v[6] * c2p) | (bf16_rne(v[7] * c2p) << 16);
            *(uint4*)(zTb + (size_t)(n0 + nl) * 64 + 8 * g) = pk;
            if (g == 0) ws[AZN_OFF + n0 + nl] = anl * s;
        }
    } else {
        int m = (blk - 256) * 256 + t;
        const float4* ep = (const float4*)(e + (size_t)m * D_);
        float s = 0.f;
        unsigned int pk[32];
#pragma unroll
        for (int k = 0; k < 16; ++k) {
            float4 v = ep[k];
            s += v.x * v.x + v.y * v.y + v.z * v.z + v.w * v.w;
            pk[2 * k]     = bf16_rne(v.x) | (bf16_rne(v.y) << 16);
            pk[2 * k + 1] = bf16_rne(v.z) | (bf16_rne(v.w) << 16);
        }
        uint4* op = (uint4*)(ebf + (size_t)m * 64);
#pragma unroll
        for (int k = 0; k < 8; ++k)
            op[k] = make_uint4(pk[4 * k], pk[4 * k + 1], pk[4 * k + 2], pk[4 * k + 3]);
        ws[AEN_OFF + m] = anl * s;
        ws[SUM_OFF + m] = 0.f;
    }
}

// grid (32,64), 256 thr: B (128 e-rows) register-resident; BOTH 128-row A-tiles
// preloaded up front (straight-line, no mid-loop prefetch); aen factored out.
__global__ __launch_bounds__(256, 2) void main_fast(float* __restrict__ ws) {
    __shared__ float lds_red[BM];
    const unsigned short* zTb = (const unsigned short*)(ws + ZTB_OFF);
    const unsigned short* ebf = (const unsigned short*)(ws + EBF_OFF);
    const float* azn = ws + AZN_OFF;
    float* sums = ws + SUM_OFF;

    const int m0 = blockIdx.x * BM;
    const int ns = blockIdx.y;
    const int t = threadIdx.x;
    const int lane = t & 63;
    const int w = t >> 6;
    const int rlo = lane & 31;
    const int kh = lane >> 5;

    const int nbase = ns * NCHUNK + w * 32;

    // ---- issue ALL loads up front: both A-tiles + azn, then B frags ----
    short8 af[NTILES][4];
    float4 aznv[NTILES][4];
#pragma unroll
    for (int tile = 0; tile < NTILES; ++tile) {
        const int nr = nbase + tile * 128;
        const size_t rb = (size_t)(nr + rlo) * 64 + (size_t)kh * 8;
#pragma unroll
        for (int ks = 0; ks < 4; ++ks)
            af[tile][ks] = *(const short8*)(zTb + rb + ks * 16);
        const int r0 = nr + 4 * kh;
#pragma unroll
        for (int rg = 0; rg < 4; ++rg)
            aznv[tile][rg] = *(const float4*)(azn + r0 + 8 * rg);
    }

    short8 bf[4][4];
#pragma unroll
    for (int mt = 0; mt < 4; ++mt) {
        int row = m0 + mt * 32 + rlo;
#pragma unroll
        for (int ks = 0; ks < 4; ++ks)
            bf[mt][ks] = *(const short8*)(ebf + (size_t)row * 64 + (ks * 2 + kh) * 8);
    }

    float sum[4] = {0.f, 0.f, 0.f, 0.f};

#pragma unroll
    for (int tile = 0; tile < NTILES; ++tile) {
        float azn_r[16];
#pragma unroll
        for (int rg = 0; rg < 4; ++rg) {
            azn_r[rg * 4 + 0] = aznv[tile][rg].x;
            azn_r[rg * 4 + 1] = aznv[tile][rg].y;
            azn_r[rg * 4 + 2] = aznv[tile][rg].z;
            azn_r[rg * 4 + 3] = aznv[tile][rg].w;
        }

        floatx16 acc[4];
#pragma unroll
        for (int mt = 0; mt < 4; ++mt)
#pragma unroll
            for (int r = 0; r < 16; ++r)
                acc[mt][r] = azn_r[r];           // aen factored out

#pragma unroll
        for (int ks = 0; ks < 4; ++ks)
#pragma unroll
            for (int mt = 0; mt < 4; ++mt)
                acc[mt] = __builtin_amdgcn_mfma_f32_32x32x16_bf16(
                    af[tile][ks], bf[mt][ks], acc[mt], 0, 0, 0);

#pragma unroll
        for (int mt = 0; mt < 4; ++mt) {
            float s = 0.f;
#pragma unroll
            for (int r = 0; r < 16; ++r) s += EXP2F(acc[mt][r]);
            sum[mt] += s;
        }
    }

#pragma unroll
    for (int mt = 0; mt < 4; ++mt) sum[mt] += __shfl_down(sum[mt], 32);

    if (t < BM) lds_red[t] = 0.f;
    __syncthreads();
    if (lane < 32) {
#pragma unroll
        for (int mt = 0; mt < 4; ++mt) atomicAdd(&lds_red[mt * 32 + rlo], sum[mt]);
    }
    __syncthreads();
    if (t < BM) atomicAdd(&sums[m0 + t], lds_red[t]);
}

__global__ void finalize_fast(const float* __restrict__ ws,
                              const float* __restrict__ lsp,
                              float* __restrict__ out) {
    __shared__ double red[256];
    const float* sums = ws + SUM_OFF;
    const float* aen = ws + AEN_OFF;
    int t = threadIdx.x;
    double local = 0.0;
#pragma unroll
    for (int j = 0; j < 16; ++j) {
        int m = t + 256 * j;
        // lse_m = ln2 * (aen'_m + log2(S_m))
        local += (double)(aen[m] + log2f(sums[m]));
    }
    red[t] = local;
    __syncthreads();
    for (int off = 128; off > 0; off >>= 1) {
        if (t < off) red[t] += red[t + off];
        __syncthreads();
    }
    if (t == 0) {
        double ls = (double)lsp[0];
        double loss = -(LN2 * red[0] / (double)M_)
                      + 0.5 * (double)D_ * (2.0 * ls - 1.0)
                      + log((double)N_);
        out[0] = (float)loss;
    }
}

extern "C" void kernel_launch(void* const* d_in, const int* in_sizes, int n_in,
                              void* d_out, int out_size, void* d_ws, size_t ws_size,
                              hipStream_t stream) {
    const float* z   = (const float*)d_in[0];
    const float* e   = (const float*)d_in[1];
    const float* lsp = (const float*)d_in[2];
    float* ws  = (float*)d_ws;
    float* out = (float*)d_out;

    hipLaunchKernelGGL(prep_kernel, dim3(272), dim3(256), 0, stream, z, e, lsp, ws);
    hipLaunchKernelGGL(main_fast, dim3(M_ / BM, NSPLIT), dim3(256), 0, stream, ws);
    hipLaunchKernelGGL(finalize_fast, dim3(1), dim3(256), 0, stream, ws, lsp, out);
}